// Round 1
// baseline (98.787 us; speedup 1.0000x reference)
//
#include <hip/hip_runtime.h>
#include <hip/hip_bf16.h>
#include <math.h>

// Chamfer distance via K-packed MFMA, B=8, N=M=8192, D=3, fp32.
//   C[m][n] = q_m.r_n - 0.5*||r_n||^2 via ONE v_mfma_f32_32x32x16_bf16:
//     lanes<32  (k0-7) : A={qh,1, ql,0}  B={rh,wh, rh,wh}
//     lanes>=32 (k8-15): A={qh,1, 0,0}   B={rl,wl, 0,0}
//   (hi/lo bf16 split; dropped ql.rl term ~2^-17 relative)
//   min_j d2 = ||q||^2_fp32 - 2*max_n C, clamped at 0.
// R7: diagnosis from counters = occupancy/latency-bound (Occupancy 25.6% ->
// only 2 blocks/CU resident; per-pipe MFMA 8%). Changes:
//   (a) refs staged to LDS via global_load_lds, 2x16KiB double buffer,
//       1 barrier / 16 iters -> global latency off the wave critical path,
//       4x less L2 traffic (refs shared by the block's 4 waves).
//       Ref layout re-tiled by prep: per 32-pt tile {hi[32]x8B, lo[32]x8B}
//       so per-lane addr = base + lane*8 (linear ds_read_b64, conflict-free).
//   (b) 3-in-flight MFMA accumulators (c3 reuses c0's slot) -> peak regs
//       ~126 <= 128 so 4 blocks/CU actually fit. Fence read-age kept >= the
//       validated 26cy minimum (s_nop 7x2 before k0-max3, s_nop 7x3 before
//       k1-max3; MFMA issue ~8cy apart on one SIMD).
//   (c) prep also stores fp32 ||q||^2 so reduce reads 4B/point, not 12B.

#define BLOCK 256
#define WAVES 4
#define QPW 64        // queries per wave (two 32-row MFMA groups)
#define NCHUNK 2      // ref-dim split across blockIdx.y
#define SREF 1024     // refs per LDS stage
#define STAGE_BYTES (SREF * 16)   // 16 KiB per buffer
#define IPS (SREF / 64)           // 16 iterations per stage

typedef short short8 __attribute__((ext_vector_type(8)));
typedef float f32x16 __attribute__((ext_vector_type(16)));
typedef unsigned int u32;
typedef __attribute__((address_space(1))) const u32 gu32;
typedef __attribute__((address_space(3))) u32 lu32;

union U16S { uint4 v; short8 s; };

__device__ __forceinline__ unsigned int bf16hi(float f) {
    __hip_bfloat16 h = __float2bfloat16(f);
    return (unsigned int)*reinterpret_cast<unsigned short*>(&h);
}
__device__ __forceinline__ float bf16f(unsigned int u) {
    unsigned short us = (unsigned short)u;
    __hip_bfloat16 h;
    *reinterpret_cast<unsigned short*>(&h) = us;
    return __bfloat162float(h);
}

__device__ __forceinline__ f32x16 mfma_bf16(short8 a, short8 b, f32x16 c) {
    f32x16 d;
    asm volatile("v_mfma_f32_32x32x16_bf16 %0, %1, %2, %3"
                 : "=v"(d) : "v"(a), "v"(b), "v"(c));
    return d;
}
// Inline asm bypasses the compiler hazard recognizer: enforce >=16 cycles
// between MFMA issue and VALU reads of dests, data-tied so nothing hoists.
__device__ __forceinline__ void mfma_fence3(f32x16& a, f32x16& b, f32x16& c) {
    asm volatile("s_nop 7\n\ts_nop 7" : "+v"(a), "+v"(b), "+v"(c));
}
__device__ __forceinline__ void mfma_fence2(f32x16& a, f32x16& b) {
    asm volatile("s_nop 7\n\ts_nop 7\n\ts_nop 7" : "+v"(a), "+v"(b));
}

__device__ __forceinline__ void gload_lds16(const void* g, void* l) {
    __builtin_amdgcn_global_load_lds((gu32*)g, (lu32*)l, 16, 0, 0);
}

// Per point:
//   recQ: one 16B record {xh|yh, zh|wh, xl|yl, zl|wl}, w = -0.5*||p||^2
//   recB: tile-grouped B-operand stream: tile t = points [32t,32t+32):
//         bytes [t*512, t*512+256)  = hi uint2 {xh|yh, zh|wh} per point
//         bytes [t*512+256, t*512+512) = lo uint2 {xl|yl, zl|wl} per point
//   q2:   fp32 ||p||^2 (exact) for the reduce pass.
__global__ void prep_kernel(const float* __restrict__ gts, const float* __restrict__ preds,
                            int nG, int nP, uint4* __restrict__ recQ,
                            unsigned char* __restrict__ recB, float* __restrict__ q2,
                            float* out) {
    const int idx = blockIdx.x * blockDim.x + threadIdx.x;
    if (idx == 0) out[0] = 0.0f;
    if (idx >= nG + nP) return;
    const float* src;
    unsigned char* rb;
    if (idx < nG) {
        src = gts + 3 * (size_t)idx;
        rb  = recB + (size_t)(idx >> 5) * 512 + (size_t)(idx & 31) * 8;
    } else {
        const int j = idx - nG;
        src = preds + 3 * (size_t)j;
        rb  = recB + (size_t)nG * 16 + (size_t)(j >> 5) * 512 + (size_t)(j & 31) * 8;
    }
    const float x = src[0], y = src[1], z = src[2];
    const float n2 = x * x + y * y + z * z;
    const float w = -0.5f * n2;
    q2[idx] = n2;
    const unsigned int xh = bf16hi(x), yh = bf16hi(y), zh = bf16hi(z), wh = bf16hi(w);
    const unsigned int xl = bf16hi(x - bf16f(xh));
    const unsigned int yl = bf16hi(y - bf16f(yh));
    const unsigned int zl = bf16hi(z - bf16f(zh));
    const unsigned int wl = bf16hi(w - bf16f(wh));
    recQ[idx] = make_uint4(xh | (yh << 16), zh | (wh << 16),
                           xl | (yl << 16), zl | (wl << 16));
    *(uint2*)(rb)       = make_uint2(xh | (yh << 16), zh | (wh << 16));
    *(uint2*)(rb + 256) = make_uint2(xl | (yl << 16), zl | (wl << 16));
}

// kpart layout: float kpart[NCHUNK][nG + nP]; slot = blockIdx.y.
__global__ void __launch_bounds__(BLOCK, 4)
nn_kernel(const uint4* __restrict__ recQ, const unsigned char* __restrict__ recB,
          float* __restrict__ kpart, int N, int M, int B) {
    const int z = blockIdx.z;
    const bool dirX = (z < B);
    const int b = dirX ? z : z - B;
    const int NQ = dirX ? N : M;
    const int NR = dirX ? M : N;
    const uint4* Qr = recQ + (dirX ? 0 : (size_t)B * N) + (size_t)b * NQ;
    const int chunk = NR / NCHUNK;
    const unsigned char* Rb = recB + (dirX ? (size_t)B * N * 16 : 0)
                              + ((size_t)b * NR + (size_t)blockIdx.y * chunk) * 16;
    const int nGP = B * (N + M);
    float* outK = kpart + (size_t)blockIdx.y * nGP + (dirX ? 0 : B * N) + (size_t)b * NQ;

    const int tid = threadIdx.x;
    const int lane = tid & 63;
    const int wave = tid >> 6;
    const int m = lane & 31;
    const bool hiK = lane >= 32;                    // this half supplies k=8..15
    const unsigned int loMask = hiK ? 0u : 0xFFFFFFFFu;
    const int qBase = (blockIdx.x * WAVES + wave) * QPW;

    // ---- A fragments (two 32-row groups)
    const uint4 q0 = Qr[qBase + m];
    const uint4 q1 = Qr[qBase + 32 + m];
    U16S a;
    a.v.x = q0.x;                                   // (qxh, qyh)
    a.v.y = (q0.y & 0xFFFFu) | 0x3F800000u;         // (qzh, 1.0bf16)
    a.v.z = q0.z & loMask;                          // (qxl, qyl) | 0
    a.v.w = q0.w & 0xFFFFu & loMask;                // (qzl, 0)   | 0
    const short8 A0 = a.s;
    a.v.x = q1.x;
    a.v.y = (q1.y & 0xFFFFu) | 0x3F800000u;
    a.v.z = q1.z & loMask;
    a.v.w = q1.w & 0xFFFFu & loMask;
    const short8 A1 = a.s;

    f32x16 zc;
    #pragma unroll
    for (int r = 0; r < 16; ++r) zc[r] = 0.0f;
    f32x16 k0, k1;
    #pragma unroll
    for (int r = 0; r < 16; ++r) { k0[r] = -INFINITY; k1[r] = -INFINITY; }

    // Staging buffers (2 x 16 KiB) alias the epilogue transpose buffer.
    __shared__ __align__(16) unsigned char smem[WAVES * 64 * 36 * 4];  // 36864 B

    // Each wave stages its 4 KiB slice: 4 x global_load_lds of 1 KiB
    // (64 lanes x 16B, linear dest = wave-uniform base + lane*16).
    const unsigned char* gsrc = Rb + (size_t)wave * 4096 + (size_t)lane * 16;
    unsigned char* lbase = smem + wave * 4096;
    auto stage_issue = [&](int s) {
        const unsigned char* g = gsrc + (size_t)s * STAGE_BYTES;
        unsigned char* l = lbase + ((s & 1) * STAGE_BYTES);
        #pragma unroll
        for (int k2 = 0; k2 < 4; ++k2)
            gload_lds16(g + k2 * 1024, l + k2 * 1024);
    };

    const int nStages = chunk / SREF;               // 4
    stage_issue(0);
    __syncthreads();                                // drains vmcnt(0)

    #pragma unroll 1
    for (int s = 0; s < nStages; ++s) {
        if (s + 1 < nStages) stage_issue(s + 1);    // fills other buffer
        // Per-lane stream: tile t at byte t*512; lane reads t*512 + lane*8
        // (lanes>=32 land on the lo half automatically). Linear b64 -> free.
        const uint2* tp = (const uint2*)(smem + ((s & 1) * STAGE_BYTES)) + lane;
        uint2 t0 = tp[0], t1 = tp[64];
        #pragma unroll
        for (int i = 0; i < IPS; ++i) {
            uint2 n0 = t0, n1 = t1;
            if (i + 1 < IPS) { n0 = tp[(i + 1) * 128]; n1 = tp[(i + 1) * 128 + 64]; }

            U16S b0, b1;
            b0.v.x = t0.x;          b0.v.y = t0.y;
            b0.v.z = t0.x & loMask; b0.v.w = t0.y & loMask;
            b1.v.x = t1.x;          b1.v.y = t1.y;
            b1.v.z = t1.x & loMask; b1.v.w = t1.y & loMask;

            // 3-in-flight accumulators: c3 reuses c0's registers (dead after
            // the k0 reduction) -> peak acc regs 48, fits 4 waves/SIMD.
            f32x16 c0 = mfma_bf16(A0, b0.s, zc);
            f32x16 c1 = mfma_bf16(A0, b1.s, zc);
            f32x16 c2 = mfma_bf16(A1, b0.s, zc);
            mfma_fence3(c0, c1, c2);
            #pragma unroll
            for (int r = 0; r < 16; ++r)
                k0[r] = fmaxf(fmaxf(c0[r], c1[r]), k0[r]);   // v_max3
            f32x16 c3 = mfma_bf16(A1, b1.s, zc);
            mfma_fence2(c2, c3);
            #pragma unroll
            for (int r = 0; r < 16; ++r)
                k1[r] = fmaxf(fmaxf(c2[r], c3[r]), k1[r]);

            t0 = n0; t1 = n1;
        }
        __syncthreads();   // drains vmcnt(0): next buffer published
    }

    // ---- epilogue: LDS transpose, then each lane max-reduces one query row.
    // C/D layout: col=lane&31, row=(r&3)+8*(r>>2)+4*(lane>>5).
    float (*sT)[64][36] = (float (*)[64][36])smem;  // +4 pad: conflict-free
    #pragma unroll
    for (int r = 0; r < 16; ++r) {
        const int row = (r & 3) + 8 * (r >> 2) + 4 * (lane >> 5);
        sT[wave][row][m]      = k0[r];              // group 0 -> rows 0..31
        sT[wave][32 + row][m] = k1[r];              // group 1 -> rows 32..63
    }
    // wave-private region; compiler inserts the lgkmcnt waits.
    const float4* rowp = (const float4*)&sT[wave][lane][0];
    float4 m01 = rowp[0];
    #pragma unroll
    for (int kk = 1; kk < 8; ++kk) {
        const float4 t = rowp[kk];
        m01.x = fmaxf(m01.x, t.x); m01.y = fmaxf(m01.y, t.y);
        m01.z = fmaxf(m01.z, t.z); m01.w = fmaxf(m01.w, t.w);
    }
    const float cmax = fmaxf(fmaxf(m01.x, m01.y), fmaxf(m01.z, m01.w));
    outK[qBase + lane] = cmax;                      // coalesced, no atomics
}

// d2 = max(0, ||q||^2 - 2*max(kpart[0], kpart[1])); weighted means, one
// atomicAdd per block. q2 precomputed fp32 in prep.
__global__ void __launch_bounds__(BLOCK)
reduce_kernel(const float* __restrict__ kpart, const float* __restrict__ q2,
              int nG, int nP, float invx, float invy, float* __restrict__ out) {
    const int total = nG + nP;
    float local = 0.0f;
    for (int idx = blockIdx.x * blockDim.x + threadIdx.x; idx < total;
         idx += gridDim.x * blockDim.x) {
        const float c = fmaxf(kpart[idx], kpart[total + idx]);
        const float inv = (idx < nG) ? invx : invy;
        local += fmaxf(q2[idx] - 2.0f * c, 0.0f) * inv;
    }
    __shared__ float waveSums[BLOCK / 64];
    float v = local;
    #pragma unroll
    for (int off = 32; off; off >>= 1) v += __shfl_xor(v, off);
    if ((threadIdx.x & 63) == 0) waveSums[threadIdx.x >> 6] = v;
    __syncthreads();
    if (threadIdx.x == 0) {
        float s = 0.0f;
        #pragma unroll
        for (int w = 0; w < BLOCK / 64; ++w) s += waveSums[w];
        atomicAdd(out, s);
    }
}

extern "C" void kernel_launch(void* const* d_in, const int* in_sizes, int n_in,
                              void* d_out, int out_size, void* d_ws, size_t ws_size,
                              hipStream_t stream) {
    const float* gts   = (const float*)d_in[0];   // [B, N, 3]
    const float* preds = (const float*)d_in[1];   // [B, M, 3]
    float* out = (float*)d_out;

    const int B = 8;
    const int N = in_sizes[0] / (B * 3);
    const int M = in_sizes[1] / (B * 3);
    const int nG = B * N, nP = B * M;

    uint4* recQ = (uint4*)d_ws;                                // (nG+nP)*16B (2 MB)
    unsigned char* recB = (unsigned char*)(recQ + nG + nP);    // (nG+nP)*16B (2 MB)
    float* kpart = (float*)(recB + (size_t)(nG + nP) * 16);    // NCHUNK*(nG+nP) (1 MB)
    float* q2    = kpart + (size_t)NCHUNK * (nG + nP);         // (nG+nP) (0.5 MB)

    prep_kernel<<<(nG + nP + BLOCK - 1) / BLOCK, BLOCK, 0, stream>>>(
        gts, preds, nG, nP, recQ, recB, q2, out);

    dim3 grid(N / (WAVES * QPW), NCHUNK, 2 * B);  // 32 x 2 x 16 = 1024 = 4/CU
    nn_kernel<<<grid, BLOCK, 0, stream>>>(recQ, recB, kpart, N, M, B);

    reduce_kernel<<<256, BLOCK, 0, stream>>>(
        kpart, q2, nG, nP, 1.0f / (float)nG, 1.0f / (float)nP, out);
}